// Round 10
// baseline (280.844 us; speedup 1.0000x reference)
//
#include <hip/hip_runtime.h>

// Linear-RNN via pure GEMM decomposition (no per-step loop).
//   h_{t+1} = h_t@M + x̄_t@S ;  o_t = x̄_t·wod + h_t·woh
//   v_i = A_i @ W̃ ; o = A_i @ T + P_{i-1}@G ; P = scan(v, M^128 powers)
// R16 = R15 (279.2us) with biggemm's per-step vmcnt(0) drain replaced by
// COUNTED waits (T4 / AITER pattern): stage next tile -> s_waitcnt vmcnt(8)
// (current tile's 8 loads done; next tile's 8 stay in flight ACROSS the
// barrier) -> s_barrier -> ds_read+MFMA -> s_barrier. vmcnt(0) only at the
// last step. sched_barrier(0) fences prevent LDS-read hoisting (rule 18).
// In-order VMEM retirement makes vmcnt(8) == "cur tile fully in LDS"
// (m135-verified semantics). kc order unchanged -> bit-identical output.
// All other kernels unchanged from R15 (BK=64 swizzled biggemm tiling,
// d=8 folded into final, G2t filler, radix-2 4-round... i.e. 3-round scan).
// NOTE: wave_gemm prefetches one 32-panel past each operand; all such reads
// stay inside the workspace (audited). Staged biggemm has no past-end reads
// (s=33 staging ends exactly at A/Bt buffer ends).

typedef __attribute__((ext_vector_type(8))) _Float16 half8;
typedef __attribute__((ext_vector_type(4))) float f32x4;
typedef unsigned short u16;

#define KTOT 2176   // 128*17
#define NBIG 640    // 512 V cols + 128 conv cols

__device__ __forceinline__ u16 f2h(float f) {
  union { _Float16 h; u16 u; } v; v.h = (_Float16)f; return v.u;
}
__device__ __forceinline__ float h2f(u16 u) {
  union { u16 u; _Float16 h; } v; v.u = u; return (float)v.h;
}

// async global->LDS 16B: LDS dest must be wave-uniform base + lane*16.
typedef const __attribute__((address_space(1))) void* as1cv;
typedef __attribute__((address_space(3))) void* as3v;
__device__ __forceinline__ void gload16(const u16* g, u16* l) {
  __builtin_amdgcn_global_load_lds((as1cv)g, (as3v)l, 16, 0, 0);
}

// wave: 64x64 tile over kc in [kc0,kcN), software-pipelined (prefetch kc+1).
// Accumulating variant: caller owns acc init.
__device__ __forceinline__ void wave_gemm_acc(const u16* __restrict__ A, int lda,
                                              const u16* __restrict__ Bt, int nstr,
                                              int kc0, int kcN, int lane,
                                              f32x4 (&acc)[4][4]) {
  const int q = lane >> 4, l15 = lane & 15;
  const u16* aP = A + (size_t)l15*lda + (size_t)kc0*32 + q*8;
  const u16* bP = Bt + ((size_t)kc0*nstr + l15)*32 + q*8;
  half8 a[4], b[4];
  #pragma unroll
  for (int rt = 0; rt < 4; ++rt) a[rt] = *(const half8*)(aP + (size_t)(rt*16)*lda);
  #pragma unroll
  for (int ct = 0; ct < 4; ++ct) b[ct] = *(const half8*)(bP + ct*512);
  for (int kc = kc0; kc < kcN; ++kc) {
    const u16* aN = aP + 32;
    const u16* bN = bP + (size_t)nstr*32;
    half8 an[4], bn[4];
    #pragma unroll
    for (int rt = 0; rt < 4; ++rt) an[rt] = *(const half8*)(aN + (size_t)(rt*16)*lda);
    #pragma unroll
    for (int ct = 0; ct < 4; ++ct) bn[ct] = *(const half8*)(bN + ct*512);
    #pragma unroll
    for (int rt = 0; rt < 4; ++rt)
      #pragma unroll
      for (int ct = 0; ct < 4; ++ct)
        acc[rt][ct] = __builtin_amdgcn_mfma_f32_16x16x32_f16(a[rt], b[ct], acc[rt][ct], 0,0,0);
    #pragma unroll
    for (int rt = 0; rt < 4; ++rt) a[rt] = an[rt];
    #pragma unroll
    for (int ct = 0; ct < 4; ++ct) b[ct] = bn[ct];
    aP = aN; bP = bN;
  }
}

__device__ __forceinline__ void wave_gemm(const u16* __restrict__ A, int lda,
                                          const u16* __restrict__ Bt, int nstr,
                                          int kc0, int kcN, int lane,
                                          f32x4 (&acc)[4][4]) {
  #pragma unroll
  for (int rt = 0; rt < 4; ++rt)
    #pragma unroll
    for (int ct = 0; ct < 4; ++ct) { f32x4 z = {0.f,0.f,0.f,0.f}; acc[rt][ct] = z; }
  wave_gemm_acc(A, lda, Bt, nstr, kc0, kcN, lane, acc);
}

// K-split reduce through LDS (48KB). Returns true for the epilogue wave (wid 0).
__device__ __forceinline__ bool ksplit_reduce(f32x4 (&acc)[4][4], float* red,
                                              int wid, int lane) {
  if (wid > 0) {
    float* dst = red + (wid - 1) * 4096;
    #pragma unroll
    for (int rt = 0; rt < 4; ++rt)
      #pragma unroll
      for (int ct = 0; ct < 4; ++ct)
        *(f32x4*)(dst + ((rt*4 + ct)*64 + lane)*4) = acc[rt][ct];
  }
  __syncthreads();
  if (wid > 0) return false;
  #pragma unroll
  for (int w = 0; w < 3; ++w)
    #pragma unroll
    for (int rt = 0; rt < 4; ++rt)
      #pragma unroll
      for (int ct = 0; ct < 4; ++ct)
        acc[rt][ct] += *(const f32x4*)(red + w*4096 + ((rt*4 + ct)*64 + lane)*4);
  return true;
}

// one 64x64 tile of a 512x512 squaring: (Mp_in @ Mt_in) -> Mp_out, Mt_out
__device__ __forceinline__ void square_tile(const u16* __restrict__ Mp_in,
                                            const u16* __restrict__ Mt_in,
                                            u16* __restrict__ Mp_out,
                                            u16* __restrict__ Mt_out,
                                            int bx, float* red, int tid) {
  const int wid = tid >> 6, lane = tid & 63, q = lane >> 4, l15 = lane & 15;
  int row0 = (bx >> 3) * 64, c0 = (bx & 7) * 64;
  f32x4 acc[4][4];
  wave_gemm(Mp_in + (size_t)row0*512, 512, Mt_in + (size_t)c0*32, 512,
            wid*4, wid*4 + 4, lane, acc);
  if (!ksplit_reduce(acc, red, wid, lane)) return;
  #pragma unroll
  for (int rt = 0; rt < 4; ++rt)
    for (int ct = 0; ct < 4; ++ct)
      for (int r = 0; r < 4; ++r) {
        int row = row0 + rt*16 + q*4 + r, col = c0 + ct*16 + l15;
        u16 v = f2h(acc[rt][ct][r]);
        Mp_out[row*512 + col] = v;
        Mt_out[(row>>5)*16384 + col*32 + (row&31)] = v;
      }
}

// ---- prep: M (plain+T32), S_r (+ Qs lag-0 seed), G col0, wod, hidden->fp16 ----
__global__ __launch_bounds__(256) void prep_kernel(
    const float* __restrict__ Wh, const float* __restrict__ Wo,
    const float* __restrict__ hidden,
    u16* __restrict__ Mp0, u16* __restrict__ Mt0,
    u16* __restrict__ Sr, float* __restrict__ G,
    float* __restrict__ wod, u16* __restrict__ Hf, u16* __restrict__ Qs) {
  int idx = blockIdx.x * 256 + threadIdx.x;
  if (idx < 262144) {                       // M[k][n] = Wh[n][16+k]
    int k = idx >> 9, n = idx & 511;
    u16 v = f2h(Wh[n*529 + 16 + k]);
    Mp0[k*512 + n] = v;
    Mt0[(k>>5)*16384 + n*32 + (k&31)] = v;
    return;
  }
  idx -= 262144;
  if (idx < 8704) {                         // S_r[q][n]; Qs lag-0 seed
    int q = idx >> 9, n = idx & 511;
    u16 v = f2h(Wh[n*529 + (q < 16 ? q : 528)]);
    Sr[idx] = v;
    Qs[idx] = v;
    return;
  }
  idx -= 8704;
  if (idx < 512) { G[idx*128 + 0] = Wo[16 + idx]; return; }
  idx -= 512;
  if (idx < 17) { wod[idx] = Wo[idx < 16 ? idx : 528]; return; }
  idx -= 17;
  if (idx < 131072) Hf[idx] = f2h(hidden[idx]);
}

// ---- level l (0..6): sq M^(2^l); Q lags [m,2m); G cols [m,2m); A-build filler ----
__global__ __launch_bounds__(256) void level_kernel(
    const u16* __restrict__ Mp_in, const u16* __restrict__ Mt_in,
    u16* __restrict__ Mp_out, u16* __restrict__ Mt_out,
    u16* __restrict__ Qs, float* __restrict__ G,
    const float* __restrict__ x, const float* __restrict__ cost,
    u16* __restrict__ A, int l) {
  __shared__ float red[12288];
  const int m = 1 << l;
  const int nq8 = (((17*m + 63) >> 6)) * 8;
  const int tid = threadIdx.x, bx = blockIdx.x;
  const int wid = tid >> 6, lane = tid & 63, q = lane >> 4, l15 = lane & 15;

  if (bx < 64) {  // square
    square_tile(Mp_in, Mt_in, Mp_out, Mt_out, bx, red, tid);
    return;
  }
  if (bx < 64 + nq8) {  // Q append: rows [0,17m) @ M^m -> [17m,34m)
    int bq = bx - 64;
    int row0 = (bq >> 3) * 64, c0 = (bq & 7) * 64;
    f32x4 acc[4][4];
    wave_gemm(Qs + (size_t)row0*512, 512, Mt_in + (size_t)c0*32, 512,
              wid*4, wid*4 + 4, lane, acc);
    if (!ksplit_reduce(acc, red, wid, lane)) return;
    int lim = 17*m;
    #pragma unroll
    for (int rt = 0; rt < 4; ++rt)
      for (int ct = 0; ct < 4; ++ct)
        for (int r = 0; r < 4; ++r) {
          int rowIn = row0 + rt*16 + q*4 + r, col = c0 + ct*16 + l15;
          if (rowIn < lim) Qs[(size_t)(lim + rowIn)*512 + col] = f2h(acc[rt][ct][r]);
        }
    return;
  }
  if (bx < 64 + nq8 + 32) {  // G append: G[:, m+c] = M^m @ G[:, c]
    int n0 = (bx - 64 - nq8) * 16;
    for (int idx = tid; idx < 16*m; idx += 256) {
      int c = idx & (m - 1), n = n0 + (idx >> l);
      const u16* mrow = Mp_in + n*512;
      float s0 = 0.f, s1 = 0.f, s2 = 0.f, s3 = 0.f;
      for (int k = 0; k < 512; k += 4) {
        s0 += h2f(mrow[k])   * G[k*128 + c];
        s1 += h2f(mrow[k+1]) * G[(k+1)*128 + c];
        s2 += h2f(mrow[k+2]) * G[(k+2)*128 + c];
        s3 += h2f(mrow[k+3]) * G[(k+3)*128 + c];
      }
      G[n*128 + m + c] = (s0 + s1) + (s2 + s3);
    }
    return;
  }
  // A-build filler: 293 WGs/level (l=6: 290), 2 rows each
  int abx = bx - (64 + nq8 + 32);
  int r = (l*293 + abx)*2 + (tid >> 7);
  if (r >= 4096) return;
  int s = tid & 127;
  int i = r >> 8, b = r & 255, t = i*128 + s;
  const float* xp = x + ((size_t)b*2048 + t)*16;
  u16* ap = A + (size_t)r*KTOT + s*17;
  #pragma unroll
  for (int p = 0; p < 16; p += 4) {
    float4 v = *(const float4*)(xp + p);
    ap[p] = f2h(v.x); ap[p+1] = f2h(v.y); ap[p+2] = f2h(v.z); ap[p+3] = f2h(v.w);
  }
  ap[16] = f2h(cost[(size_t)b*2048 + t]);
}

// ---- Cb[q][lam] = sum_k Sr[q][k] * G[k][lam] ----
__global__ void cbar_kernel(const u16* __restrict__ Sr, const float* __restrict__ G,
                            float* __restrict__ Cb) {
  int qq = blockIdx.x, lam = threadIdx.x;
  float s0 = 0.f, s1 = 0.f, s2 = 0.f, s3 = 0.f;
  for (int k = 0; k < 512; k += 4) {
    s0 += h2f(Sr[qq*512 + k])   * G[k*128 + lam];
    s1 += h2f(Sr[qq*512 + k+1]) * G[(k+1)*128 + lam];
    s2 += h2f(Sr[qq*512 + k+2]) * G[(k+2)*128 + lam];
    s3 += h2f(Sr[qq*512 + k+3]) * G[(k+3)*128 + lam];
  }
  Cb[qq*128 + lam] = (s0 + s1) + (s2 + s3);
}

// ---- build B (T32, 640 cols) + Gt (T32 of G) ----
__global__ void bbuild_kernel(const u16* __restrict__ Qs, const float* __restrict__ Cb,
                              const float* __restrict__ wod, const float* __restrict__ G,
                              u16* __restrict__ Bt, u16* __restrict__ Gt) {
  int idx = blockIdx.x * 256 + threadIdx.x;
  if (idx < KTOT * NBIG) {
    int krow = idx / NBIG, n = idx - krow * NBIG;
    int kc = krow >> 5, kk = krow & 31;
    int s = krow / 17, qq = krow - s * 17;
    u16 v;
    if (n < 512) {
      v = Qs[(size_t)((127 - s)*17 + qq)*512 + n];
    } else {
      int j = n - 512;
      if (s < j)       v = f2h(Cb[qq*128 + (j - 1 - s)]);
      else if (s == j) v = f2h(wod[qq]);
      else             v = 0;
    }
    Bt[(size_t)kc*(NBIG*32) + n*32 + kk] = v;
    return;
  }
  idx -= KTOT * NBIG;
  if (idx < 512*128) {
    int k = idx >> 7, j = idx & 127;
    Gt[(k>>5)*4096 + j*32 + (k&31)] = f2h(G[k*128 + j]);
  }
}

// ---- big GEMM [4096x640x2176], LDS-staged, BM=BN=128, BK=64 (34 steps),
//      XOR-swizzled LDS, COUNTED vmcnt (never 0 in the loop; T4 pattern).
//      Grid: 160 gemm WGs (32 rowg x 5 colg) + 64 square fillers
//      (M^128 -> M^256). LDS 64KB/WG. ----
__global__ __launch_bounds__(256) void biggemm_kernel(const u16* __restrict__ A,
                                                      const u16* __restrict__ Bt,
                                                      u16* __restrict__ V0,
                                                      float* __restrict__ out,
                                                      const u16* __restrict__ Mp7,
                                                      const u16* __restrict__ Mt7,
                                                      u16* __restrict__ Mp8,
                                                      u16* __restrict__ Mt8) {
  __shared__ __align__(16) char smem[65536];
  const int bx = blockIdx.x, tid = threadIdx.x;
  if (bx >= 160) {
    float* red = (float*)smem;
    square_tile(Mp7, Mt7, Mp8, Mt8, bx - 160, red, tid);
    return;
  }
  // LDS: sA[2][128*64], sB[2][128*64] (B stored [col][64k]) = 64KB, linear.
  // Logical layout is swizzled: lds[row][c] holds G[row][c ^ ((row&7)<<3)].
  u16* sA = (u16*)smem;
  u16* sB = (u16*)(smem + 32768);
  const int rowg = bx & 31, colg = bx >> 5;
  const int row0 = rowg * 128, c0 = colg * 128;
  const int wid = tid >> 6, lane = tid & 63;
  const int q = lane >> 4, l15 = lane & 15;
  const int wr = wid >> 1, wc = wid & 1;   // 2x2 waves, each 64x64
  // staging decomposition: per call j (j=0..3) thread covers
  // (row/col)=32j+tr, k-group tc8; source col pre-swizzled by (tr&7)<<3.
  const int tr = tid >> 3, tc8 = (tid & 7) * 8;
  const int swc = tc8 ^ ((tr & 7) << 3);   // swizzled source k-offset [0,64)
  // A: row-major, lda=KTOT. per step s: +64s. per call j: +32j rows.
  const u16* gA0 = A + (size_t)(row0 + tr) * KTOT + swc;
  // B: T32 panels [kc][n][32]; swc selects panel (swc>>5) and kk (swc&31).
  const u16* gB0 = Bt + ((size_t)(swc >> 5) * NBIG + (c0 + tr)) * 32 + (swc & 31);
  const int lofs = tid * 8;                // linear LDS dest per call

  f32x4 acc[4][4];
  #pragma unroll
  for (int rt = 0; rt < 4; ++rt)
    #pragma unroll
    for (int ct = 0; ct < 4; ++ct) { f32x4 z = {0.f,0.f,0.f,0.f}; acc[rt][ct] = z; }

  // stage step 0 into buf 0 (8 loads in flight)
  #pragma unroll
  for (int j = 0; j < 4; ++j) {
    gload16(gA0 + (size_t)(32*j)*KTOT, sA + j*2048 + lofs);
    gload16(gB0 + j*1024,              sB + j*2048 + lofs);
  }

  int cur = 0;
  for (int s = 0; s < 34; ++s) {
    if (s + 1 < 34) {  // stage next step into other buffer (async DMA)
      const u16* ga = gA0 + (s + 1) * 64;
      const u16* gb = gB0 + (size_t)(s + 1) * (NBIG * 64);
      u16* dA = sA + (cur ^ 1) * 8192;
      u16* dB = sB + (cur ^ 1) * 8192;
      #pragma unroll
      for (int j = 0; j < 4; ++j) {
        gload16(ga + (size_t)(32*j)*KTOT, dA + j*2048 + lofs);
        gload16(gb + j*1024,              dB + j*2048 + lofs);
      }
      // wait only the CURRENT tile's 8 loads; next tile's 8 stay in flight
      asm volatile("s_waitcnt vmcnt(8)" ::: "memory");
    } else {
      asm volatile("s_waitcnt vmcnt(0)" ::: "memory");
    }
    __builtin_amdgcn_s_barrier();          // all waves' cur tile in LDS
    __builtin_amdgcn_sched_barrier(0);     // no LDS-read hoist above barrier
    const u16* pA = sA + cur * 8192 + (wr*64 + l15) * 64;
    const u16* pB = sB + cur * 8192 + (wc*64 + l15) * 64;
    const int rsw = (l15 & 7) << 3;      // read-side swizzle (row&7 == l15&7)
    #pragma unroll
    for (int kc = 0; kc < 2; ++kc) {
      const int kcol = (kc*32 + q*8) ^ rsw;
      half8 a[4], b[4];
      #pragma unroll
      for (int rt = 0; rt < 4; ++rt) a[rt] = *(const half8*)(pA + rt*1024 + kcol);
      #pragma unroll
      for (int ct = 0; ct < 4; ++ct) b[ct] = *(const half8*)(pB + ct*1024 + kcol);
      #pragma unroll
      for (int rt = 0; rt < 4; ++rt)
        #pragma unroll
        for (int ct = 0; ct < 4; ++ct)
          acc[rt][ct] = __builtin_amdgcn_mfma_f32_16x16x32_f16(a[rt], b[ct], acc[rt][ct], 0,0,0);
    }
    __builtin_amdgcn_sched_barrier(0);     // reads/MFMA stay above end barrier
    __builtin_amdgcn_s_barrier();          // all reads done -> safe overwrite
    cur ^= 1;
  }

  #pragma unroll
  for (int rt = 0; rt < 4; ++rt)
    for (int ct = 0; ct < 4; ++ct)
      for (int r = 0; r < 4; ++r) {
        int rg = row0 + wr*64 + rt*16 + q*4 + r;
        int col = c0 + wc*64 + ct*16 + l15;
        if (col < 512) {
          V0[(size_t)rg*512 + col] = f2h(acc[rt][ct][r]);
        } else {
          int j = col - 512, b = rg & 255, i = rg >> 8;
          out[(size_t)b*2048 + i*128 + j] = acc[rt][ct][r];
        }
      }
}

// ---- scan round: Vdst[i] = Vsrc[i-d]@M^(128d) + Vsrc[i]; i-d==-1 uses Hf.
//      filler==1 (grid 576): bx>=512 square Mp_si@Mt_si -> Mp_so/Mt_so.
//      filler==2 (grid 528): bx>=512 G2 tile: Mp_so(T32) = Mp_si @ Mt_si,
//      output 512x128 (G2t layout), 16 WGs. ----
__global__ __launch_bounds__(256) void scan_kernel(const u16* __restrict__ Vsrc,
                                                   u16* __restrict__ Vdst,
                                                   const u16* __restrict__ Mt,
                                                   const u16* __restrict__ Hf, int d,
                                                   int filler,
                                                   const u16* __restrict__ Mp_si,
                                                   const u16* __restrict__ Mt_si,
                                                   u16* __restrict__ Mp_so,
                                                   u16* __restrict__ Mt_so) {
  __shared__ float red[12288];
  const int bx = blockIdx.x, tid = threadIdx.x;
  const int wid = tid >> 6, lane = tid & 63;
  const int q = lane >> 4, l15 = lane & 15;
  if (bx >= 512) {
    if (filler == 1) {
      square_tile(Mp_si, Mt_si, Mp_so, Mt_so, bx - 512, red, tid);
    } else {
      // G2 tile: out 512x128 = Mp_si(512x512) @ Gt(=Mt_si, T32 nstr=128)
      int hbx = bx - 512;                 // [0,16)
      int rowg = hbx >> 1, colg = hbx & 1;
      int row0 = rowg*64, c0 = colg*64;
      f32x4 acc[4][4];
      wave_gemm(Mp_si + (size_t)row0*512, 512, Mt_si + (size_t)c0*32, 128,
                wid*4, wid*4 + 4, lane, acc);
      if (!ksplit_reduce(acc, red, wid, lane)) return;
      #pragma unroll
      for (int rt = 0; rt < 4; ++rt)
        for (int ct = 0; ct < 4; ++ct)
          for (int r = 0; r < 4; ++r) {
            int n = row0 + rt*16 + q*4 + r, j = c0 + ct*16 + l15;
            Mp_so[(n>>5)*4096 + j*32 + (n&31)] = f2h(acc[rt][ct][r]);  // G2t T32
          }
    }
    return;
  }
  int i = bx >> 5, rowg = (bx >> 3) & 3, colg = bx & 7;
  int row0 = rowg*64, c0 = colg*64;
  int src_i = i - d;
  if (src_i >= -1) {
    const u16* Asrc = (src_i >= 0) ? Vsrc + (size_t)(src_i*256 + row0)*512
                                   : Hf + (size_t)row0*512;
    f32x4 acc[4][4];
    wave_gemm(Asrc, 512, Mt + (size_t)c0*32, 512, wid*4, wid*4 + 4, lane, acc);
    if (!ksplit_reduce(acc, red, wid, lane)) return;
    #pragma unroll
    for (int rt = 0; rt < 4; ++rt)
      for (int ct = 0; ct < 4; ++ct)
        for (int r = 0; r < 4; ++r) {
          int rg = i*256 + row0 + rt*16 + q*4 + r, col = c0 + ct*16 + l15;
          Vdst[(size_t)rg*512 + col] = f2h(acc[rt][ct][r] + h2f(Vsrc[(size_t)rg*512 + col]));
        }
  } else {
    for (int it = tid; it < 512; it += 256) {
      int rl = it >> 3, cu = it & 7;
      size_t o = (size_t)(i*256 + row0 + rl)*512 + colg*64 + cu*8;
      *(uint4*)(Vdst + o) = *(const uint4*)(Vsrc + o);
    }
  }
}

// ---- final (reads W = V1 after rounds d=1,2,4):
//      bx<128: out[b][i*128+j] += P_{i-1}@G where P_j = W[j] (+ 2nd unit
//        (j==7?Hf:W[j-8])@G2 for j>=7, G2 = M^1024@G).
//      bx in [128,160): h_final = P_15 = W[7]@M^1024 + W[15]. ----
__global__ __launch_bounds__(256) void final_kernel(const u16* __restrict__ W,
                                                    const u16* __restrict__ Hf,
                                                    const u16* __restrict__ Gt,
                                                    const u16* __restrict__ G2t,
                                                    const u16* __restrict__ Mt10,
                                                    float* __restrict__ out) {
  __shared__ float red[12288];
  const int bx = blockIdx.x, tid = threadIdx.x;
  const int wid = tid >> 6, lane = tid & 63;
  const int q = lane >> 4, l15 = lane & 15;
  if (bx >= 128) {  // h_final: 32 WGs over 256x512, P_15 = W[7]@M^1024 + W[15]
    int hbx = bx - 128;                  // [0,32)
    int rowg = hbx >> 3, colg = hbx & 7;
    int row0 = rowg*64, c0 = colg*64;    // row0 in [0,256)
    f32x4 acc[4][4];
    wave_gemm(W + (size_t)(1792 + row0)*512, 512, Mt10 + (size_t)c0*32, 512,
              wid*4, wid*4 + 4, lane, acc);
    if (!ksplit_reduce(acc, red, wid, lane)) return;
    #pragma unroll
    for (int rt = 0; rt < 4; ++rt)
      for (int ct = 0; ct < 4; ++ct)
        for (int r = 0; r < 4; ++r) {
          int row = row0 + rt*16 + q*4 + r, col = c0 + ct*16 + l15;
          out[524288 + (size_t)row*512 + col] =
              acc[rt][ct][r] + h2f(W[(size_t)(3840 + row)*512 + col]);
        }
    return;
  }
  int rowg = bx >> 1, colg = bx & 1;
  int row0 = rowg*64, c0 = colg*64;      // stack row0 in [0,4096)
  int s = rowg >> 2;                     // stack chunk: 0 -> Hf, s>=1 -> W[s-1]
  const u16* Abase = (s == 0) ? (Hf + (size_t)row0*512)
                              : (W + (size_t)(row0 - 256)*512);
  f32x4 acc[4][4];
  wave_gemm(Abase, 512, Gt + (size_t)c0*32, 128, wid*4, wid*4 + 4, lane, acc);
  if (s >= 8) {  // P_{s-1} needs (s==8 ? Hf : W[s-9]) @ G2
    int ro = row0 & 255;                 // offset within chunk
    const u16* A2 = (s == 8) ? (Hf + (size_t)ro*512)
                             : (W + (size_t)((s - 9)*256 + ro)*512);
    wave_gemm_acc(A2, 512, G2t + (size_t)c0*32, 128, wid*4, wid*4 + 4, lane, acc);
  }
  if (!ksplit_reduce(acc, red, wid, lane)) return;
  #pragma unroll
  for (int rt = 0; rt < 4; ++rt)
    for (int ct = 0; ct < 4; ++ct)
      for (int r = 0; r < 4; ++r) {
        int rg = row0 + rt*16 + q*4 + r, j = c0 + ct*16 + l15;
        int b = rg & 255, i = rg >> 8;
        out[(size_t)b*2048 + i*128 + j] += acc[rt][ct][r];
      }
}

extern "C" void kernel_launch(void* const* d_in, const int* in_sizes, int n_in,
                              void* d_out, int out_size, void* d_ws, size_t ws_size,
                              hipStream_t stream) {
  (void)in_sizes; (void)n_in; (void)out_size; (void)ws_size;
  const float* x      = (const float*)d_in[0];
  const float* hidden = (const float*)d_in[1];
  const float* cost   = (const float*)d_in[2];
  const float* Wo     = (const float*)d_in[3];
  const float* Wh     = (const float*)d_in[4];
  float* out = (float*)d_out;
  char* ws = (char*)d_ws;

  auto Mp = [&](int l){ return (u16*)(ws + (size_t)l*524288); };
  auto Mt = [&](int l){ return (u16*)(ws + 5767168 + (size_t)l*524288); };
  u16*   Qs  = (u16*)(ws + 11534336);   // 2176 x 512
  float* G   = (float*)(ws + 13762560); // 512 x 128
  u16*   Sr  = (u16*)(ws + 14024704);   // 17 x 512
  float* wod = (float*)(ws + 14057472); // 17
  float* Cb  = (float*)(ws + 14057728); // 17 x 128
  u16*   Hf  = (u16*)(ws + 14074112);   // 256 x 512
  u16*   Bt  = (u16*)(ws + 14336256);   // T32 2176 x 640
  u16*   Gt  = (u16*)(ws + 17121536);   // T32 512 x 128
  u16*   A   = (u16*)(ws + 17252608);   // 4096 x 2176
  u16*   V0  = (u16*)(ws + 35078400);   // 4096 x 512
  u16*   V1  = (u16*)(ws + 39272704);   // 4096 x 512
  u16*   G2t = Mp(0);                   // G2 (T32 512x128) in dead M^1 slot

  prep_kernel<<<1573, 256, 0, stream>>>(Wh, Wo, hidden, Mp(0), Mt(0), Sr, G, wod, Hf, Qs);
  for (int l = 0; l <= 6; ++l) {
    int m = 1 << l;
    int nq8 = ((17*m + 63) >> 6) * 8;
    int abn = (l == 6) ? 290 : 293;
    int grid = 64 + nq8 + 32 + abn;
    level_kernel<<<grid, 256, 0, stream>>>(Mp(l), Mt(l), Mp(l+1), Mt(l+1),
                                           Qs, G, x, cost, A, l);
  }
  cbar_kernel<<<17, 128, 0, stream>>>(Sr, G, Cb);
  bbuild_kernel<<<(KTOT*NBIG + 512*128 + 255)/256, 256, 0, stream>>>(Qs, Cb, wod, G, Bt, Gt);
  // biggemm (LDS-staged, BK=64, swizzled, counted vmcnt) + square M^128->M^256
  biggemm_kernel<<<224, 256, 0, stream>>>(A, Bt, V0, out, Mp(7), Mt(7), Mp(8), Mt(8));
  // scan d=1 (M^128) + square M^256->M^512
  scan_kernel<<<576, 256, 0, stream>>>(V0, V1, Mt(7), Hf, 1, 1, Mp(8), Mt(8), Mp(9), Mt(9));
  // scan d=2 (M^256) + square M^512->M^1024
  scan_kernel<<<576, 256, 0, stream>>>(V1, V0, Mt(8), Hf, 2, 1, Mp(9), Mt(9), Mp(10), Mt(10));
  // scan d=4 (M^512) + G2t = (M^1024 @ G) in T32  [16 filler WGs]
  scan_kernel<<<528, 256, 0, stream>>>(V0, V1, Mt(9), Hf, 4, 2, Mp(10), Gt, G2t, nullptr);
  // final: reads W=V1; folds the old d=8 round
  final_kernel<<<160, 256, 0, stream>>>(V1, Hf, Gt, G2t, Mt(10), out);
}

// Round 11
// 236.966 us; speedup vs baseline: 1.1852x; 1.1852x over previous
//
#include <hip/hip_runtime.h>

// Linear-RNN via pure GEMM decomposition (no per-step loop).
//   h_{t+1} = h_t@M + x̄_t@S ;  o_t = x̄_t·wod + h_t·woh
//   v_i = A_i @ W̃ ; o = A_i @ T + P_{i-1}@G ; P = scan(v, M^128 powers)
// R17 = R15 (279.2us; R16's counted-vmcnt measured neutral -> reverted) with
// G-append GEMM-ified: the old 32-WG scalar dot loop (l=6: ~14K cy/thread,
// the level critical path) becomes 8 MFMA WGs computing
// Gt[:, m+c] = M^m @ Gt[:, c] (c<m) via wave_gemm. G now lives ONLY as Gt
// (T32 fp16), maintained incrementally: prep writes col0, levels write cols
// [m,2m) in T32, cbar reads Gt, bbuild drops its Gt-build tail. MFMA col-j
// output depends only on B col j, so the unwritten garbage cols (c>=m) of
// the 64-wide tile are harmless. Everything else identical to R15/R14
// (BK=64 swizzled biggemm, d=8 folded into final, G2t filler).
// NOTE: wave_gemm prefetches one 32-panel past each operand; all such reads
// stay inside the workspace (audited; Gt's nstr=128 prefetch spills into the
// adjacent A buffer exactly like final_kernel's existing Gt use). Staged
// biggemm has no past-end reads (s=33 staging ends exactly at buffer ends).

typedef __attribute__((ext_vector_type(8))) _Float16 half8;
typedef __attribute__((ext_vector_type(4))) float f32x4;
typedef unsigned short u16;

#define KTOT 2176   // 128*17
#define NBIG 640    // 512 V cols + 128 conv cols

__device__ __forceinline__ u16 f2h(float f) {
  union { _Float16 h; u16 u; } v; v.h = (_Float16)f; return v.u;
}
__device__ __forceinline__ float h2f(u16 u) {
  union { u16 u; _Float16 h; } v; v.u = u; return (float)v.h;
}

// async global->LDS 16B: LDS dest must be wave-uniform base + lane*16.
typedef const __attribute__((address_space(1))) void* as1cv;
typedef __attribute__((address_space(3))) void* as3v;
__device__ __forceinline__ void gload16(const u16* g, u16* l) {
  __builtin_amdgcn_global_load_lds((as1cv)g, (as3v)l, 16, 0, 0);
}

// wave: 64x64 tile over kc in [kc0,kcN), software-pipelined (prefetch kc+1).
// Accumulating variant: caller owns acc init.
__device__ __forceinline__ void wave_gemm_acc(const u16* __restrict__ A, int lda,
                                              const u16* __restrict__ Bt, int nstr,
                                              int kc0, int kcN, int lane,
                                              f32x4 (&acc)[4][4]) {
  const int q = lane >> 4, l15 = lane & 15;
  const u16* aP = A + (size_t)l15*lda + (size_t)kc0*32 + q*8;
  const u16* bP = Bt + ((size_t)kc0*nstr + l15)*32 + q*8;
  half8 a[4], b[4];
  #pragma unroll
  for (int rt = 0; rt < 4; ++rt) a[rt] = *(const half8*)(aP + (size_t)(rt*16)*lda);
  #pragma unroll
  for (int ct = 0; ct < 4; ++ct) b[ct] = *(const half8*)(bP + ct*512);
  for (int kc = kc0; kc < kcN; ++kc) {
    const u16* aN = aP + 32;
    const u16* bN = bP + (size_t)nstr*32;
    half8 an[4], bn[4];
    #pragma unroll
    for (int rt = 0; rt < 4; ++rt) an[rt] = *(const half8*)(aN + (size_t)(rt*16)*lda);
    #pragma unroll
    for (int ct = 0; ct < 4; ++ct) bn[ct] = *(const half8*)(bN + ct*512);
    #pragma unroll
    for (int rt = 0; rt < 4; ++rt)
      #pragma unroll
      for (int ct = 0; ct < 4; ++ct)
        acc[rt][ct] = __builtin_amdgcn_mfma_f32_16x16x32_f16(a[rt], b[ct], acc[rt][ct], 0,0,0);
    #pragma unroll
    for (int rt = 0; rt < 4; ++rt) a[rt] = an[rt];
    #pragma unroll
    for (int ct = 0; ct < 4; ++ct) b[ct] = bn[ct];
    aP = aN; bP = bN;
  }
}

__device__ __forceinline__ void wave_gemm(const u16* __restrict__ A, int lda,
                                          const u16* __restrict__ Bt, int nstr,
                                          int kc0, int kcN, int lane,
                                          f32x4 (&acc)[4][4]) {
  #pragma unroll
  for (int rt = 0; rt < 4; ++rt)
    #pragma unroll
    for (int ct = 0; ct < 4; ++ct) { f32x4 z = {0.f,0.f,0.f,0.f}; acc[rt][ct] = z; }
  wave_gemm_acc(A, lda, Bt, nstr, kc0, kcN, lane, acc);
}

// K-split reduce through LDS (48KB). Returns true for the epilogue wave (wid 0).
__device__ __forceinline__ bool ksplit_reduce(f32x4 (&acc)[4][4], float* red,
                                              int wid, int lane) {
  if (wid > 0) {
    float* dst = red + (wid - 1) * 4096;
    #pragma unroll
    for (int rt = 0; rt < 4; ++rt)
      #pragma unroll
      for (int ct = 0; ct < 4; ++ct)
        *(f32x4*)(dst + ((rt*4 + ct)*64 + lane)*4) = acc[rt][ct];
  }
  __syncthreads();
  if (wid > 0) return false;
  #pragma unroll
  for (int w = 0; w < 3; ++w)
    #pragma unroll
    for (int rt = 0; rt < 4; ++rt)
      #pragma unroll
      for (int ct = 0; ct < 4; ++ct)
        acc[rt][ct] += *(const f32x4*)(red + w*4096 + ((rt*4 + ct)*64 + lane)*4);
  return true;
}

// one 64x64 tile of a 512x512 squaring: (Mp_in @ Mt_in) -> Mp_out, Mt_out
__device__ __forceinline__ void square_tile(const u16* __restrict__ Mp_in,
                                            const u16* __restrict__ Mt_in,
                                            u16* __restrict__ Mp_out,
                                            u16* __restrict__ Mt_out,
                                            int bx, float* red, int tid) {
  const int wid = tid >> 6, lane = tid & 63, q = lane >> 4, l15 = lane & 15;
  int row0 = (bx >> 3) * 64, c0 = (bx & 7) * 64;
  f32x4 acc[4][4];
  wave_gemm(Mp_in + (size_t)row0*512, 512, Mt_in + (size_t)c0*32, 512,
            wid*4, wid*4 + 4, lane, acc);
  if (!ksplit_reduce(acc, red, wid, lane)) return;
  #pragma unroll
  for (int rt = 0; rt < 4; ++rt)
    for (int ct = 0; ct < 4; ++ct)
      for (int r = 0; r < 4; ++r) {
        int row = row0 + rt*16 + q*4 + r, col = c0 + ct*16 + l15;
        u16 v = f2h(acc[rt][ct][r]);
        Mp_out[row*512 + col] = v;
        Mt_out[(row>>5)*16384 + col*32 + (row&31)] = v;
      }
}

// ---- prep: M (plain+T32), S_r (+ Qs lag-0 seed), Gt col0, wod, hidden->fp16 ----
__global__ __launch_bounds__(256) void prep_kernel(
    const float* __restrict__ Wh, const float* __restrict__ Wo,
    const float* __restrict__ hidden,
    u16* __restrict__ Mp0, u16* __restrict__ Mt0,
    u16* __restrict__ Sr, u16* __restrict__ Gt,
    float* __restrict__ wod, u16* __restrict__ Hf, u16* __restrict__ Qs) {
  int idx = blockIdx.x * 256 + threadIdx.x;
  if (idx < 262144) {                       // M[k][n] = Wh[n][16+k]
    int k = idx >> 9, n = idx & 511;
    u16 v = f2h(Wh[n*529 + 16 + k]);
    Mp0[k*512 + n] = v;
    Mt0[(k>>5)*16384 + n*32 + (k&31)] = v;
    return;
  }
  idx -= 262144;
  if (idx < 8704) {                         // S_r[q][n]; Qs lag-0 seed
    int q = idx >> 9, n = idx & 511;
    u16 v = f2h(Wh[n*529 + (q < 16 ? q : 528)]);
    Sr[idx] = v;
    Qs[idx] = v;
    return;
  }
  idx -= 8704;
  if (idx < 512) {                          // Gt col 0 (T32)
    Gt[(idx >> 5)*4096 + (idx & 31)] = f2h(Wo[16 + idx]);
    return;
  }
  idx -= 512;
  if (idx < 17) { wod[idx] = Wo[idx < 16 ? idx : 528]; return; }
  idx -= 17;
  if (idx < 131072) Hf[idx] = f2h(hidden[idx]);
}

// ---- level l (0..6): sq M^(2^l); Q lags [m,2m); Gt cols [m,2m) via MFMA;
//      A-build filler ----
__global__ __launch_bounds__(256) void level_kernel(
    const u16* __restrict__ Mp_in, const u16* __restrict__ Mt_in,
    u16* __restrict__ Mp_out, u16* __restrict__ Mt_out,
    u16* __restrict__ Qs, u16* __restrict__ Gt,
    const float* __restrict__ x, const float* __restrict__ cost,
    u16* __restrict__ A, int l) {
  __shared__ float red[12288];
  const int m = 1 << l;
  const int nq8 = (((17*m + 63) >> 6)) * 8;
  const int tid = threadIdx.x, bx = blockIdx.x;
  const int wid = tid >> 6, lane = tid & 63, q = lane >> 4, l15 = lane & 15;

  if (bx < 64) {  // square
    square_tile(Mp_in, Mt_in, Mp_out, Mt_out, bx, red, tid);
    return;
  }
  if (bx < 64 + nq8) {  // Q append: rows [0,17m) @ M^m -> [17m,34m)
    int bq = bx - 64;
    int row0 = (bq >> 3) * 64, c0 = (bq & 7) * 64;
    f32x4 acc[4][4];
    wave_gemm(Qs + (size_t)row0*512, 512, Mt_in + (size_t)c0*32, 512,
              wid*4, wid*4 + 4, lane, acc);
    if (!ksplit_reduce(acc, red, wid, lane)) return;
    int lim = 17*m;
    #pragma unroll
    for (int rt = 0; rt < 4; ++rt)
      for (int ct = 0; ct < 4; ++ct)
        for (int r = 0; r < 4; ++r) {
          int rowIn = row0 + rt*16 + q*4 + r, col = c0 + ct*16 + l15;
          if (rowIn < lim) Qs[(size_t)(lim + rowIn)*512 + col] = f2h(acc[rt][ct][r]);
        }
    return;
  }
  if (bx < 64 + nq8 + 8) {  // Gt append: Gt[:, m+c] = M^m @ Gt[:, c], c < m
    int rowg = bx - 64 - nq8;            // [0,8)
    int row0 = rowg * 64;
    f32x4 acc[4][4];
    wave_gemm(Mp_in + (size_t)row0*512, 512, Gt, 128,
              wid*4, wid*4 + 4, lane, acc);
    if (!ksplit_reduce(acc, red, wid, lane)) return;
    #pragma unroll
    for (int rt = 0; rt < 4; ++rt)
      for (int ct = 0; ct < 4; ++ct)
        for (int r = 0; r < 4; ++r) {
          int n = row0 + rt*16 + q*4 + r, c = ct*16 + l15;
          if (c < m) Gt[(n>>5)*4096 + (m + c)*32 + (n&31)] = f2h(acc[rt][ct][r]);
        }
    return;
  }
  // A-build filler: 293 WGs/level (l=6: 290), 2 rows each
  int abx = bx - (64 + nq8 + 8);
  int r = (l*293 + abx)*2 + (tid >> 7);
  if (r >= 4096) return;
  int s = tid & 127;
  int i = r >> 8, b = r & 255, t = i*128 + s;
  const float* xp = x + ((size_t)b*2048 + t)*16;
  u16* ap = A + (size_t)r*KTOT + s*17;
  #pragma unroll
  for (int p = 0; p < 16; p += 4) {
    float4 v = *(const float4*)(xp + p);
    ap[p] = f2h(v.x); ap[p+1] = f2h(v.y); ap[p+2] = f2h(v.z); ap[p+3] = f2h(v.w);
  }
  ap[16] = f2h(cost[(size_t)b*2048 + t]);
}

// ---- Cb[q][lam] = sum_k Sr[q][k] * Gt[k][lam] ----
__global__ void cbar_kernel(const u16* __restrict__ Sr, const u16* __restrict__ Gt,
                            float* __restrict__ Cb) {
  int qq = blockIdx.x, lam = threadIdx.x;
  float s0 = 0.f, s1 = 0.f, s2 = 0.f, s3 = 0.f;
  for (int k = 0; k < 512; k += 4) {
    const u16* gp = Gt + (k >> 5)*4096 + lam*32 + (k & 31);
    s0 += h2f(Sr[qq*512 + k])   * h2f(gp[0]);
    s1 += h2f(Sr[qq*512 + k+1]) * h2f(gp[1]);
    s2 += h2f(Sr[qq*512 + k+2]) * h2f(gp[2]);
    s3 += h2f(Sr[qq*512 + k+3]) * h2f(gp[3]);
  }
  Cb[qq*128 + lam] = (s0 + s1) + (s2 + s3);
}

// ---- build B (T32, 640 cols) ----
__global__ void bbuild_kernel(const u16* __restrict__ Qs, const float* __restrict__ Cb,
                              const float* __restrict__ wod,
                              u16* __restrict__ Bt) {
  int idx = blockIdx.x * 256 + threadIdx.x;
  if (idx < KTOT * NBIG) {
    int krow = idx / NBIG, n = idx - krow * NBIG;
    int kc = krow >> 5, kk = krow & 31;
    int s = krow / 17, qq = krow - s * 17;
    u16 v;
    if (n < 512) {
      v = Qs[(size_t)((127 - s)*17 + qq)*512 + n];
    } else {
      int j = n - 512;
      if (s < j)       v = f2h(Cb[qq*128 + (j - 1 - s)]);
      else if (s == j) v = f2h(wod[qq]);
      else             v = 0;
    }
    Bt[(size_t)kc*(NBIG*32) + n*32 + kk] = v;
  }
}

// ---- big GEMM [4096x640x2176], LDS-staged, BM=BN=128, BK=64 (34 steps),
//      XOR-swizzled LDS (col ^= (row&7)<<3 elems; pre-swizzled global src).
//      Grid: 160 gemm WGs (32 rowg x 5 colg) + 64 square fillers
//      (M^128 -> M^256). LDS 64KB/WG. ----
__global__ __launch_bounds__(256) void biggemm_kernel(const u16* __restrict__ A,
                                                      const u16* __restrict__ Bt,
                                                      u16* __restrict__ V0,
                                                      float* __restrict__ out,
                                                      const u16* __restrict__ Mp7,
                                                      const u16* __restrict__ Mt7,
                                                      u16* __restrict__ Mp8,
                                                      u16* __restrict__ Mt8) {
  __shared__ __align__(16) char smem[65536];
  const int bx = blockIdx.x, tid = threadIdx.x;
  if (bx >= 160) {
    float* red = (float*)smem;
    square_tile(Mp7, Mt7, Mp8, Mt8, bx - 160, red, tid);
    return;
  }
  // LDS: sA[2][128*64], sB[2][128*64] (B stored [col][64k]) = 64KB, linear.
  // Logical layout is swizzled: lds[row][c] holds G[row][c ^ ((row&7)<<3)].
  u16* sA = (u16*)smem;
  u16* sB = (u16*)(smem + 32768);
  const int rowg = bx & 31, colg = bx >> 5;
  const int row0 = rowg * 128, c0 = colg * 128;
  const int wid = tid >> 6, lane = tid & 63;
  const int q = lane >> 4, l15 = lane & 15;
  const int wr = wid >> 1, wc = wid & 1;   // 2x2 waves, each 64x64
  // staging decomposition: per call j (j=0..3) thread covers
  // (row/col)=32j+tr, k-group tc8; source col pre-swizzled by (tr&7)<<3.
  const int tr = tid >> 3, tc8 = (tid & 7) * 8;
  const int swc = tc8 ^ ((tr & 7) << 3);   // swizzled source k-offset [0,64)
  // A: row-major, lda=KTOT. per step s: +64s. per call j: +32j rows.
  const u16* gA0 = A + (size_t)(row0 + tr) * KTOT + swc;
  // B: T32 panels [kc][n][32]; swc selects panel (swc>>5) and kk (swc&31).
  const u16* gB0 = Bt + ((size_t)(swc >> 5) * NBIG + (c0 + tr)) * 32 + (swc & 31);
  const int lofs = tid * 8;                // linear LDS dest per call

  f32x4 acc[4][4];
  #pragma unroll
  for (int rt = 0; rt < 4; ++rt)
    #pragma unroll
    for (int ct = 0; ct < 4; ++ct) { f32x4 z = {0.f,0.f,0.f,0.f}; acc[rt][ct] = z; }

  // stage step 0 into buf 0
  #pragma unroll
  for (int j = 0; j < 4; ++j) {
    gload16(gA0 + (size_t)(32*j)*KTOT, sA + j*2048 + lofs);
    gload16(gB0 + j*1024,              sB + j*2048 + lofs);
  }
  __syncthreads();

  int cur = 0;
  for (int s = 0; s < 34; ++s) {
    if (s + 1 < 34) {  // stage next step into other buffer (async DMA)
      const u16* ga = gA0 + (s + 1) * 64;
      const u16* gb = gB0 + (size_t)(s + 1) * (NBIG * 64);
      u16* dA = sA + (cur ^ 1) * 8192;
      u16* dB = sB + (cur ^ 1) * 8192;
      #pragma unroll
      for (int j = 0; j < 4; ++j) {
        gload16(ga + (size_t)(32*j)*KTOT, dA + j*2048 + lofs);
        gload16(gb + j*1024,              dB + j*2048 + lofs);
      }
    }
    const u16* pA = sA + cur * 8192 + (wr*64 + l15) * 64;
    const u16* pB = sB + cur * 8192 + (wc*64 + l15) * 64;
    const int rsw = (l15 & 7) << 3;      // read-side swizzle (row&7 == l15&7)
    #pragma unroll
    for (int kc = 0; kc < 2; ++kc) {
      const int kcol = (kc*32 + q*8) ^ rsw;
      half8 a[4], b[4];
      #pragma unroll
      for (int rt = 0; rt < 4; ++rt) a[rt] = *(const half8*)(pA + rt*1024 + kcol);
      #pragma unroll
      for (int ct = 0; ct < 4; ++ct) b[ct] = *(const half8*)(pB + ct*1024 + kcol);
      #pragma unroll
      for (int rt = 0; rt < 4; ++rt)
        #pragma unroll
        for (int ct = 0; ct < 4; ++ct)
          acc[rt][ct] = __builtin_amdgcn_mfma_f32_16x16x32_f16(a[rt], b[ct], acc[rt][ct], 0,0,0);
    }
    __syncthreads();   // drains vmcnt (staging done) + all ds_reads of cur
    cur ^= 1;
  }

  #pragma unroll
  for (int rt = 0; rt < 4; ++rt)
    for (int ct = 0; ct < 4; ++ct)
      for (int r = 0; r < 4; ++r) {
        int rg = row0 + wr*64 + rt*16 + q*4 + r;
        int col = c0 + wc*64 + ct*16 + l15;
        if (col < 512) {
          V0[(size_t)rg*512 + col] = f2h(acc[rt][ct][r]);
        } else {
          int j = col - 512, b = rg & 255, i = rg >> 8;
          out[(size_t)b*2048 + i*128 + j] = acc[rt][ct][r];
        }
      }
}

// ---- scan round: Vdst[i] = Vsrc[i-d]@M^(128d) + Vsrc[i]; i-d==-1 uses Hf.
//      filler==1 (grid 576): bx>=512 square Mp_si@Mt_si -> Mp_so/Mt_so.
//      filler==2 (grid 528): bx>=512 G2 tile: Mp_so(T32) = Mp_si @ Mt_si,
//      output 512x128 (G2t layout), 16 WGs. ----
__global__ __launch_bounds__(256) void scan_kernel(const u16* __restrict__ Vsrc,
                                                   u16* __restrict__ Vdst,
                                                   const u16* __restrict__ Mt,
                                                   const u16* __restrict__ Hf, int d,
                                                   int filler,
                                                   const u16* __restrict__ Mp_si,
                                                   const u16* __restrict__ Mt_si,
                                                   u16* __restrict__ Mp_so,
                                                   u16* __restrict__ Mt_so) {
  __shared__ float red[12288];
  const int bx = blockIdx.x, tid = threadIdx.x;
  const int wid = tid >> 6, lane = tid & 63;
  const int q = lane >> 4, l15 = lane & 15;
  if (bx >= 512) {
    if (filler == 1) {
      square_tile(Mp_si, Mt_si, Mp_so, Mt_so, bx - 512, red, tid);
    } else {
      // G2 tile: out 512x128 = Mp_si(512x512) @ Gt(=Mt_si, T32 nstr=128)
      int hbx = bx - 512;                 // [0,16)
      int rowg = hbx >> 1, colg = hbx & 1;
      int row0 = rowg*64, c0 = colg*64;
      f32x4 acc[4][4];
      wave_gemm(Mp_si + (size_t)row0*512, 512, Mt_si + (size_t)c0*32, 128,
                wid*4, wid*4 + 4, lane, acc);
      if (!ksplit_reduce(acc, red, wid, lane)) return;
      #pragma unroll
      for (int rt = 0; rt < 4; ++rt)
        for (int ct = 0; ct < 4; ++ct)
          for (int r = 0; r < 4; ++r) {
            int n = row0 + rt*16 + q*4 + r, j = c0 + ct*16 + l15;
            Mp_so[(n>>5)*4096 + j*32 + (n&31)] = f2h(acc[rt][ct][r]);  // G2t T32
          }
    }
    return;
  }
  int i = bx >> 5, rowg = (bx >> 3) & 3, colg = bx & 7;
  int row0 = rowg*64, c0 = colg*64;
  int src_i = i - d;
  if (src_i >= -1) {
    const u16* Asrc = (src_i >= 0) ? Vsrc + (size_t)(src_i*256 + row0)*512
                                   : Hf + (size_t)row0*512;
    f32x4 acc[4][4];
    wave_gemm(Asrc, 512, Mt + (size_t)c0*32, 512, wid*4, wid*4 + 4, lane, acc);
    if (!ksplit_reduce(acc, red, wid, lane)) return;
    #pragma unroll
    for (int rt = 0; rt < 4; ++rt)
      for (int ct = 0; ct < 4; ++ct)
        for (int r = 0; r < 4; ++r) {
          int rg = i*256 + row0 + rt*16 + q*4 + r, col = c0 + ct*16 + l15;
          Vdst[(size_t)rg*512 + col] = f2h(acc[rt][ct][r] + h2f(Vsrc[(size_t)rg*512 + col]));
        }
  } else {
    for (int it = tid; it < 512; it += 256) {
      int rl = it >> 3, cu = it & 7;
      size_t o = (size_t)(i*256 + row0 + rl)*512 + colg*64 + cu*8;
      *(uint4*)(Vdst + o) = *(const uint4*)(Vsrc + o);
    }
  }
}

// ---- final (reads W = V1 after rounds d=1,2,4):
//      bx<128: out[b][i*128+j] += P_{i-1}@G where P_j = W[j] (+ 2nd unit
//        (j==7?Hf:W[j-8])@G2 for j>=7, G2 = M^1024@G).
//      bx in [128,160): h_final = P_15 = W[7]@M^1024 + W[15]. ----
__global__ __launch_bounds__(256) void final_kernel(const u16* __restrict__ W,
                                                    const u16* __restrict__ Hf,
                                                    const u16* __restrict__ Gt,
                                                    const u16* __restrict__ G2t,
                                                    const u16* __restrict__ Mt10,
                                                    float* __restrict__ out) {
  __shared__ float red[12288];
  const int bx = blockIdx.x, tid = threadIdx.x;
  const int wid = tid >> 6, lane = tid & 63;
  const int q = lane >> 4, l15 = lane & 15;
  if (bx >= 128) {  // h_final: 32 WGs over 256x512, P_15 = W[7]@M^1024 + W[15]
    int hbx = bx - 128;                  // [0,32)
    int rowg = hbx >> 3, colg = hbx & 7;
    int row0 = rowg*64, c0 = colg*64;    // row0 in [0,256)
    f32x4 acc[4][4];
    wave_gemm(W + (size_t)(1792 + row0)*512, 512, Mt10 + (size_t)c0*32, 512,
              wid*4, wid*4 + 4, lane, acc);
    if (!ksplit_reduce(acc, red, wid, lane)) return;
    #pragma unroll
    for (int rt = 0; rt < 4; ++rt)
      for (int ct = 0; ct < 4; ++ct)
        for (int r = 0; r < 4; ++r) {
          int row = row0 + rt*16 + q*4 + r, col = c0 + ct*16 + l15;
          out[524288 + (size_t)row*512 + col] =
              acc[rt][ct][r] + h2f(W[(size_t)(3840 + row)*512 + col]);
        }
    return;
  }
  int rowg = bx >> 1, colg = bx & 1;
  int row0 = rowg*64, c0 = colg*64;      // stack row0 in [0,4096)
  int s = rowg >> 2;                     // stack chunk: 0 -> Hf, s>=1 -> W[s-1]
  const u16* Abase = (s == 0) ? (Hf + (size_t)row0*512)
                              : (W + (size_t)(row0 - 256)*512);
  f32x4 acc[4][4];
  wave_gemm(Abase, 512, Gt + (size_t)c0*32, 128, wid*4, wid*4 + 4, lane, acc);
  if (s >= 8) {  // P_{s-1} needs (s==8 ? Hf : W[s-9]) @ G2
    int ro = row0 & 255;                 // offset within chunk
    const u16* A2 = (s == 8) ? (Hf + (size_t)ro*512)
                             : (W + (size_t)((s - 9)*256 + ro)*512);
    wave_gemm_acc(A2, 512, G2t + (size_t)c0*32, 128, wid*4, wid*4 + 4, lane, acc);
  }
  if (!ksplit_reduce(acc, red, wid, lane)) return;
  #pragma unroll
  for (int rt = 0; rt < 4; ++rt)
    for (int ct = 0; ct < 4; ++ct)
      for (int r = 0; r < 4; ++r) {
        int rg = row0 + rt*16 + q*4 + r, j = c0 + ct*16 + l15;
        int b = rg & 255, i = rg >> 8;
        out[(size_t)b*2048 + i*128 + j] += acc[rt][ct][r];
      }
}

extern "C" void kernel_launch(void* const* d_in, const int* in_sizes, int n_in,
                              void* d_out, int out_size, void* d_ws, size_t ws_size,
                              hipStream_t stream) {
  (void)in_sizes; (void)n_in; (void)out_size; (void)ws_size;
  const float* x      = (const float*)d_in[0];
  const float* hidden = (const float*)d_in[1];
  const float* cost   = (const float*)d_in[2];
  const float* Wo     = (const float*)d_in[3];
  const float* Wh     = (const float*)d_in[4];
  float* out = (float*)d_out;
  char* ws = (char*)d_ws;

  auto Mp = [&](int l){ return (u16*)(ws + (size_t)l*524288); };
  auto Mt = [&](int l){ return (u16*)(ws + 5767168 + (size_t)l*524288); };
  u16*   Qs  = (u16*)(ws + 11534336);   // 2176 x 512
  u16*   Sr  = (u16*)(ws + 14024704);   // 17 x 512
  float* wod = (float*)(ws + 14057472); // 17
  float* Cb  = (float*)(ws + 14057728); // 17 x 128
  u16*   Hf  = (u16*)(ws + 14074112);   // 256 x 512
  u16*   Bt  = (u16*)(ws + 14336256);   // T32 2176 x 640
  u16*   Gt  = (u16*)(ws + 17121536);   // T32 512 x 128 (fp16, incremental)
  u16*   A   = (u16*)(ws + 17252608);   // 4096 x 2176
  u16*   V0  = (u16*)(ws + 35078400);   // 4096 x 512
  u16*   V1  = (u16*)(ws + 39272704);   // 4096 x 512
  u16*   G2t = Mp(0);                   // G2 (T32 512x128) in dead M^1 slot

  prep_kernel<<<1573, 256, 0, stream>>>(Wh, Wo, hidden, Mp(0), Mt(0), Sr, Gt, wod, Hf, Qs);
  for (int l = 0; l <= 6; ++l) {
    int m = 1 << l;
    int nq8 = ((17*m + 63) >> 6) * 8;
    int abn = (l == 6) ? 290 : 293;
    int grid = 64 + nq8 + 8 + abn;
    level_kernel<<<grid, 256, 0, stream>>>(Mp(l), Mt(l), Mp(l+1), Mt(l+1),
                                           Qs, Gt, x, cost, A, l);
  }
  cbar_kernel<<<17, 128, 0, stream>>>(Sr, Gt, Cb);
  bbuild_kernel<<<(KTOT*NBIG + 255)/256, 256, 0, stream>>>(Qs, Cb, wod, Bt);
  // biggemm (LDS-staged, BK=64, swizzled) + square M^128->M^256
  biggemm_kernel<<<224, 256, 0, stream>>>(A, Bt, V0, out, Mp(7), Mt(7), Mp(8), Mt(8));
  // scan d=1 (M^128) + square M^256->M^512
  scan_kernel<<<576, 256, 0, stream>>>(V0, V1, Mt(7), Hf, 1, 1, Mp(8), Mt(8), Mp(9), Mt(9));
  // scan d=2 (M^256) + square M^512->M^1024
  scan_kernel<<<576, 256, 0, stream>>>(V1, V0, Mt(8), Hf, 2, 1, Mp(9), Mt(9), Mp(10), Mt(10));
  // scan d=4 (M^512) + G2t = (M^1024 @ G) in T32  [16 filler WGs]
  scan_kernel<<<528, 256, 0, stream>>>(V0, V1, Mt(9), Hf, 4, 2, Mp(10), Gt, G2t, nullptr);
  // final: reads W=V1; folds the old d=8 round
  final_kernel<<<160, 256, 0, stream>>>(V1, Hf, Gt, G2t, Mt(10), out);
}